// Round 10
// baseline (138.322 us; speedup 1.0000x reference)
//
#include <hip/hip_runtime.h>
#include <climits>

#define VOXD 25
#define SLOT3 (VOXD*VOXD*VOXD)      // 15625
#define SLOTS (2*SLOT3)             // 31250
#define NCLS 8
#define NCODE 16
#define HB 2048                     // radix bins (11 bits)
#define BPC 64                      // fallback blocks per code (grid = 1024)
#define TILE 1024                   // cluster tile entries in LDS
#define CSTRIDE SLOT3               // per-code bucket capacity

struct Scalars {
  double hub;
  double cosSum;
  int n1;
  int nmd;
  float thresh;
  int done;
  int done2;   // k_loss_sel finalize counter
};

__device__ __forceinline__ int voxslot(int b, int vx, int vy, int vz) {
  return ((b * VOXD + vx) * VOXD + vy) * VOXD + vz;
}

// 256-thread (4-wave) inclusive block scan; ws[4] shared scratch.
__device__ __forceinline__ int block_scan256(int v, int* ws) {
  int lane = threadIdx.x & 63, w = threadIdx.x >> 6;
  int s = v;
  #pragma unroll
  for (int off = 1; off < 64; off <<= 1) {
    int t = __shfl_up(s, off, 64);
    if (lane >= off) s += t;
  }
  if (lane == 63) ws[w] = s;
  __syncthreads();
  int add = 0;
  #pragma unroll
  for (int q = 0; q < 4; ++q) if (q < w) add += ws[q];
  __syncthreads();
  return s + add;
}

// ---------------- K1: scatter + zero of the "late" scratch region ----------------
// The late region (codeCnt/missCnt/ghist/gh2A/gh2B/uCnt/sc) is not touched by
// this kernel, so zeroing it here is race-free; consumers run in later dispatches.
__global__ void k_scatter(const float* __restrict__ grid, const int* __restrict__ label,
                          const int* __restrict__ batch,
                          unsigned long long* vA, unsigned long long* vB, int* lmask,
                          int* blCnt, float* blSum, int* lateZero, int nzi, int n) {
  __shared__ int sCnt[NCODE];
  __shared__ float sSum[3 * NCODE];
  int tid = threadIdx.x;
  {
    int g = blockIdx.x * 256 + tid;
    int stride = gridDim.x * 256;
    for (int t = g; t < nzi; t += stride) lateZero[t] = 0;
  }
  if (tid < NCODE) sCnt[tid] = 0;
  if (tid < 3 * NCODE) sSum[tid] = 0.f;
  __syncthreads();
  int i = blockIdx.x * blockDim.x + tid;
  if (i < n) {
    float gx = grid[3*i], gy = grid[3*i+1], gz = grid[3*i+2];
    int ix = (int)gx, iy = (int)gy, iz = (int)gz;   // coords are exact small ints
    int vx = (int)floorf(gx * (1.0f/16.0f));
    int vy = (int)floorf(gy * (1.0f/16.0f));
    int vz = (int)floorf(gz * (1.0f/16.0f));
    int b = batch[i], l = label[i];
    int s = voxslot(b, vx, vy, vz);
    atomicAdd(&vA[s], ((unsigned long long)(unsigned)ix << 32) | (unsigned)iy);
    atomicAdd(&vB[s], ((unsigned long long)(unsigned)iz << 24) | 1ULL);
    atomicOr(&lmask[s], 1 << l);
    int bl = b * NCLS + l;
    atomicAdd(&sCnt[bl], 1);
    atomicAdd(&sSum[3*bl], gx); atomicAdd(&sSum[3*bl+1], gy); atomicAdd(&sSum[3*bl+2], gz);
  }
  __syncthreads();
  if (tid < NCODE && sCnt[tid] != 0) atomicAdd(&blCnt[tid], sCnt[tid]);
  if (tid < 3 * NCODE && sSum[tid] != 0.f) atomicAdd(&blSum[tid], sSum[tid]);
}

// ---------------- K2: fused prep + probe targets + miss lists + hist -------------
// Prep phase: each block decodes a slice of <=256 slots from the raw tables and
// appends pure clusters to per-code buckets (exact k_prep lc/lb aggregation).
// Consumer (k_fallback) is a later dispatch -> no intra-kernel ordering needed.
// Bucket order changes vs legacy, but k_fallback's min over slot-unique keys is
// order-invariant => bit-identical results.
// Probe phase: decodes vA/vB/lmask on the fly (identical __fdiv_rn chains);
// hit test reduces to lmask[slot] == (1<<l).
__global__ void __launch_bounds__(256) k_targets_prep(
    const float* __restrict__ grid, const int* __restrict__ label,
    const int* __restrict__ batch,
    const unsigned long long* __restrict__ vA, const unsigned long long* __restrict__ vB,
    const int* __restrict__ lmask,
    const int* __restrict__ blCnt, const float* __restrict__ blSum,
    float4* pC, int* codeCnt,
    float* tgt, float* mag, int* ghist,
    int* missPart, int* missCnt, int mstride, int spb, int n) {
  __shared__ int wCnt[4][NCODE];
  __shared__ int gBase[NCODE];
  __shared__ int h[HB];
  __shared__ int lc[NCODE];
  __shared__ int lb[NCODE];
  int tid = threadIdx.x, lane = tid & 63, w = tid >> 6;
  for (int t = tid; t < HB; t += 256) h[t] = 0;
  if (tid < NCODE) lc[tid] = 0;
  __syncthreads();

  // ---- prep phase: slot slice [blockIdx.x*spb, +spb), spb <= 256 ----
  int code = -1, lpos = 0;
  int sSlot = blockIdx.x * spb + tid;
  float pcx = 0.f, pcy = 0.f, pcz = 0.f;
  if (tid < spb && sSlot < SLOTS) {
    unsigned long long bq = vB[sSlot];
    unsigned c = (unsigned)(bq & 0xFFFFFFULL);
    if (c > 0) {
      unsigned long long aq = vA[sSlot];
      float fc = (float)c;
      pcx = __fdiv_rn((float)(unsigned)(aq >> 32), fc);
      pcy = __fdiv_rn((float)(unsigned)(aq & 0xFFFFFFFFULL), fc);
      pcz = __fdiv_rn((float)(unsigned)(bq >> 24), fc);
      int m = lmask[sSlot];
      bool pure = (m & (m - 1)) == 0;
      if (pure) {
        int lbl = __ffs(m) - 1;
        code = (sSlot / SLOT3) * NCLS + lbl;
        lpos = atomicAdd(&lc[code], 1);
      }
    }
  }
  __syncthreads();
  if (tid < NCODE) lb[tid] = (lc[tid] > 0) ? atomicAdd(&codeCnt[tid], lc[tid]) : 0;
  __syncthreads();
  if (code >= 0) {
    int pos = code * CSTRIDE + lb[code] + lpos;
    pC[pos] = make_float4(pcx, pcy, pcz, __int_as_float(sSlot));
  }

  // ---- probe phase (legacy semantics, raw-table decode) ----
  int i = blockIdx.x * blockDim.x + tid;
  bool miss = false;
  int mcode = -1;

  if (i < n) {
    float gx = grid[3*i], gy = grid[3*i+1], gz = grid[3*i+2];
    int vx = (int)floorf(gx * (1.0f/16.0f));
    int vy = (int)floorf(gy * (1.0f/16.0f));
    int vz = (int)floorf(gz * (1.0f/16.0f));
    int b = batch[i], l = label[i];
    int s = voxslot(b, vx, vy, vz);

    // own cluster center (cnt>0 guaranteed: this point is in the slot)
    unsigned long long bqo = vB[s];
    unsigned co = (unsigned)(bqo & 0xFFFFFFULL);
    unsigned long long aqo = vA[s];
    float fco = (float)co;
    float ownx = __fdiv_rn((float)(unsigned)(aqo >> 32), fco);
    float owny = __fdiv_rn((float)(unsigned)(aqo & 0xFFFFFFFFULL), fco);
    float ownz = __fdiv_rn((float)(unsigned)(bqo >> 24), fco);
    int mo = lmask[s];
    bool purept = (mo & (mo - 1)) == 0;

    int bl = b * NCLS + l;
    float fbc = (float)max(blCnt[bl], 1);
    float gcx = __fdiv_rn(blSum[3*bl],   fbc);
    float gcy = __fdiv_rn(blSum[3*bl+1], fbc);
    float gcz = __fdiv_rn(blSum[3*bl+2], fbc);

    float dx = __fsub_rn(gcx, ownx);
    float dy = __fsub_rn(gcy, owny);
    float dz = __fsub_rn(gcz, ownz);
    int sgx = (dx > 0.f) ? 1 : ((dx < 0.f) ? -1 : 0);
    int sgy = (dy > 0.f) ? 1 : ((dy < 0.f) ? -1 : 0);
    int sgz = (dz > 0.f) ? 1 : ((dz < 0.f) ? -1 : 0);

    int ax1 = vx + sgx,     ay1 = vy + sgy,     az1 = vz + sgz;
    int ax2 = vx + 2 * sgx, ay2 = vy + 2 * sgy, az2 = vz + 2 * sgz;
    bool v1 = (unsigned)ax1 < (unsigned)VOXD && (unsigned)ay1 < (unsigned)VOXD &&
              (unsigned)az1 < (unsigned)VOXD;
    bool v2 = (unsigned)ax2 < (unsigned)VOXD && (unsigned)ay2 < (unsigned)VOXD &&
              (unsigned)az2 < (unsigned)VOXD;

    int s1 = v1 ? voxslot(b, ax1, ay1, az1) : 0;
    int s2 = v2 ? voxslot(b, ax2, ay2, az2) : 0;
    // hit <=> probed slot is pure with exactly this label <=> lmask == 1<<l
    bool hit1 = v1 && (lmask[s1] == (1 << l));
    bool hit2 = v2 && (lmask[s2] == (1 << l));

    float tx, ty, tz;
    if (hit1) {
      unsigned long long bq1 = vB[s1];
      unsigned c1c = (unsigned)(bq1 & 0xFFFFFFULL);
      unsigned long long aq1 = vA[s1];
      float fc1 = (float)c1c;
      tx = __fdiv_rn((float)(unsigned)(aq1 >> 32), fc1);
      ty = __fdiv_rn((float)(unsigned)(aq1 & 0xFFFFFFFFULL), fc1);
      tz = __fdiv_rn((float)(unsigned)(bq1 >> 24), fc1);
    } else if (hit2) {
      unsigned long long bq2 = vB[s2];
      unsigned c2c = (unsigned)(bq2 & 0xFFFFFFULL);
      unsigned long long aq2 = vA[s2];
      float fc2 = (float)c2c;
      tx = __fdiv_rn((float)(unsigned)(aq2 >> 32), fc2);
      ty = __fdiv_rn((float)(unsigned)(aq2 & 0xFFFFFFFFULL), fc2);
      tz = __fdiv_rn((float)(unsigned)(bq2 >> 24), fc2);
    } else {
      tx = gx; ty = gy; tz = gz;
    }

    tgt[3*i] = tx; tgt[3*i+1] = ty; tgt[3*i+2] = tz;
    miss = (!purept && !hit1 && !hit2);
    if (miss) {
      mcode = bl;
    } else {
      float tox = __fsub_rn(tx, gx), toy = __fsub_rn(ty, gy), toz = __fsub_rn(tz, gz);
      float ssq = __fadd_rn(__fadd_rn(__fmul_rn(tox,tox), __fmul_rn(toy,toy)),
                            __fmul_rn(toz,toz));
      float m = (ssq > 0.f) ? sqrtf(ssq) : 0.f;
      mag[i] = m;
      atomicAdd(&h[__float_as_uint(m) >> 21], 1);
    }
  }
  int myrank = 0;
  #pragma unroll
  for (int c = 0; c < NCODE; ++c) {
    unsigned long long mb = __ballot(mcode == c);
    if (lane == 0) wCnt[w][c] = __popcll(mb);
    if (mcode == c) myrank = __popcll(mb & ((1ULL << lane) - 1ULL));
  }
  __syncthreads();
  if (tid < NCODE) {
    int tot = wCnt[0][tid] + wCnt[1][tid] + wCnt[2][tid] + wCnt[3][tid];
    gBase[tid] = (tot > 0) ? atomicAdd(&missCnt[tid], tot) : 0;
  }
  __syncthreads();
  if (miss) {
    int base = gBase[mcode];
    for (int q = 0; q < 4; ++q) if (q < w) base += wCnt[q][mcode];
    missPart[mcode * mstride + base + myrank] = i;
  }
  for (int t = tid; t < HB; t += 256) {
    int c = h[t];
    if (c != 0) atomicAdd(&ghist[t], c);
  }
}

// ---------------- K3: fallback, 64 misses/block, cluster-split across 4 waves ----
// (Round-8-verified structure; winning center decoded from raw tables.)
__global__ void __launch_bounds__(256) k_fallback(
    const float* __restrict__ grid,
    const float4* __restrict__ pC,
    const unsigned long long* __restrict__ vA, const unsigned long long* __restrict__ vB,
    const int* __restrict__ codeCnt,
    const int* __restrict__ missPart, const int* __restrict__ missCnt,
    float* tgt, float* mag, int* ghist, int mstride) {
  __shared__ float4 tile4[TILE];                 // 16 KB {x,y,z,c2}
  __shared__ int    stile[TILE];                 //  4 KB slot ids
  __shared__ unsigned long long bkeyw[4][64];    //  2 KB per-wave best keys
  __shared__ int h[HB];                          //  8 KB per-block histogram
  int tid = threadIdx.x, lane = tid & 63, w = tid >> 6;
  int c = blockIdx.x / BPC;
  int y = blockIdx.x % BPC;
  int mc = missCnt[c];
  if (y * 64 >= mc) return;                      // uniform early-out
  int cc = codeCnt[c];
  int j0 = c * CSTRIDE;
  const int* mlist = missPart + c * mstride;

  for (int t = tid; t < HB; t += 256) h[t] = 0;
  __syncthreads();

  for (int t0 = y * 64; t0 < mc; t0 += BPC * 64) {
    int t = t0 + lane;
    bool valid = (t < mc);
    int idx = 0;
    float gx = 0.f, gy = 0.f, gz = 0.f, p2 = 0.f;
    if (valid) {
      idx = mlist[t];
      gx = grid[3*idx]; gy = grid[3*idx+1]; gz = grid[3*idx+2];
      p2 = __fadd_rn(__fadd_rn(__fmul_rn(gx,gx), __fmul_rn(gy,gy)),
                     __fmul_rn(gz,gz));
    }
    unsigned long long key = 0xFFFFFFFFFFFFFFFFULL;
    for (int tb = 0; tb < cc; tb += TILE) {
      int m = min(TILE, cc - tb);
      __syncthreads();
      for (int j = tid; j < m; j += 256) {
        float4 cl = pC[j0 + tb + j];
        float c2 = __fadd_rn(__fadd_rn(__fmul_rn(cl.x,cl.x), __fmul_rn(cl.y,cl.y)),
                             __fmul_rn(cl.z,cl.z));
        tile4[j] = make_float4(cl.x, cl.y, cl.z, c2);
        stile[j] = __float_as_int(cl.w);
      }
      __syncthreads();
      #pragma unroll 4
      for (int j = w; j < m; j += 4) {
        float4 cl = tile4[j];                    // broadcast read
        float dot = __fadd_rn(__fadd_rn(__fmul_rn(gx,cl.x), __fmul_rn(gy,cl.y)),
                              __fmul_rn(gz,cl.z));
        float d2 = __fadd_rn(__fsub_rn(p2, __fmul_rn(2.0f, dot)), cl.w);
        unsigned fb = __float_as_uint(d2);
        fb = (fb >> 31) ? ~fb : (fb | 0x80000000u);
        unsigned long long k2 = ((unsigned long long)fb << 32) | (unsigned)stile[j];
        if (k2 < key) key = k2;
      }
    }
    bkeyw[w][lane] = key;
    __syncthreads();
    if (w == 0 && valid) {
      unsigned long long k0 = bkeyw[0][lane];
      unsigned long long k1 = bkeyw[1][lane];
      unsigned long long k2_ = bkeyw[2][lane];
      unsigned long long k3 = bkeyw[3][lane];
      unsigned long long kk = k0 < k1 ? k0 : k1;
      unsigned long long kh = k2_ < k3 ? k2_ : k3;
      if (kh < kk) kk = kh;
      float mv = 0.f;
      if (cc > 0) {
        int slot = (int)(unsigned)(kk & 0xFFFFFFFFULL);
        unsigned long long bq = vB[slot];
        unsigned cw = (unsigned)(bq & 0xFFFFFFULL);   // >0 for pure slots
        unsigned long long aq = vA[slot];
        float fc = (float)cw;
        float cx_ = __fdiv_rn((float)(unsigned)(aq >> 32), fc);
        float cy_ = __fdiv_rn((float)(unsigned)(aq & 0xFFFFFFFFULL), fc);
        float cz_ = __fdiv_rn((float)(unsigned)(bq >> 24), fc);
        tgt[3*idx] = cx_; tgt[3*idx+1] = cy_; tgt[3*idx+2] = cz_;
        float tox = __fsub_rn(cx_, gx), toy = __fsub_rn(cy_, gy),
              toz = __fsub_rn(cz_, gz);
        float ssq = __fadd_rn(__fadd_rn(__fmul_rn(tox,tox), __fmul_rn(toy,toy)),
                              __fmul_rn(toz,toz));
        mv = (ssq > 0.f) ? sqrtf(ssq) : 0.f;
      }
      mag[idx] = mv;
      atomicAdd(&h[__float_as_uint(mv) >> 21], 1);
    }
    __syncthreads();                             // bkeyw/h reuse next pass
  }

  // flush aggregated histogram
  for (int t = tid; t < HB; t += 256) {
    int cv = h[t];
    if (cv != 0) atomicAdd(&ghist[t], cv);
  }
}

// ---------------- K4: loss + exact quantile, distributed finalize prep -----------
// (Round-9-verified.)
__global__ void __launch_bounds__(256) k_loss_sel(
    const float* __restrict__ pred, const float* __restrict__ grid,
    const float* __restrict__ tgt, const float* __restrict__ mag,
    const int* __restrict__ ghist, int* gh2A, int* gh2B,
    unsigned* dBits, double2* dHC, int* uCnt,
    Scalars* sc, float* out, int n, int nblocks, int r0, int r1, double tfrac) {
  __shared__ int h[HB];            // 8 KB (step-2 hA2; tail reuse)
  __shared__ int h2[HB];           // 8 KB (step-2 hB2; tail reuse)
  __shared__ int ws[4];
  __shared__ int s_misc[8];
  __shared__ double shH[256];
  __shared__ double shC[256];
  __shared__ int shN[256];
  __shared__ int shM[256];
  __shared__ int sLast;
  __shared__ float sTh;
  int tid = threadIdx.x, lane = tid & 63;

  // ---- step 1: coarse bins from ghist (every block; identical results) ----
  int base8 = tid * 8;
  {
    int cbin[8];
    int s = 0;
    #pragma unroll
    for (int k = 0; k < 8; ++k) { cbin[k] = ghist[base8 + k]; s += cbin[k]; }
    int incl = block_scan256(s, ws);
    int lo = incl - s;
    if (r0 >= lo && r0 < lo + s) {
      int acc = lo;
      #pragma unroll
      for (int k = 0; k < 8; ++k) {
        if (r0 < acc + cbin[k]) { s_misc[0] = base8 + k; s_misc[1] = r0 - acc; break; }
        acc += cbin[k];
      }
    }
    if (r1 >= lo && r1 < lo + s) {
      int acc = lo;
      #pragma unroll
      for (int k = 0; k < 8; ++k) {
        if (r1 < acc + cbin[k]) { s_misc[2] = base8 + k; s_misc[3] = r1 - acc; break; }
        acc += cbin[k];
      }
    }
  }
  __syncthreads();
  int binA = s_misc[0], rA = s_misc[1], binB = s_misc[2], rB = s_misc[3];

  // ---- step 2: classify; sure sums; deferred -> contributions + mid LDS hist ----
  for (int t = tid; t < HB; t += 256) { h[t] = 0; h2[t] = 0; }
  __syncthreads();

  int i = blockIdx.x * 256 + tid;
  double hub = 0.0, cs = 0.0;
  int c1 = 0, cmd = 0;
  bool dfr = false;
  unsigned bits = 0;
  double dhub = 0.0, dcs = 0.0;
  if (i < n) {
    float m = mag[i];
    bits = __float_as_uint(m);
    int cb = (int)(bits >> 21);
    bool boundary = (cb == binA || cb == binB);
    if (boundary || cb < binA) {
      float tox = __fsub_rn(tgt[3*i],   grid[3*i]);
      float toy = __fsub_rn(tgt[3*i+1], grid[3*i+1]);
      float toz = __fsub_rn(tgt[3*i+2], grid[3*i+2]);
      float px = pred[3*i], py = pred[3*i+1], pz = pred[3*i+2];
      float d0 = __fsub_rn(px, tox), d1 = __fsub_rn(py, toy), d2 = __fsub_rn(pz, toz);
      float a0 = fabsf(d0), a1 = fabsf(d1), a2 = fabsf(d2);
      float h0 = (a0 < 1.f) ? __fmul_rn(__fmul_rn(0.5f, d0), d0) : __fsub_rn(a0, 0.5f);
      float h1 = (a1 < 1.f) ? __fmul_rn(__fmul_rn(0.5f, d1), d1) : __fsub_rn(a1, 0.5f);
      float h2v = (a2 < 1.f) ? __fmul_rn(__fmul_rn(0.5f, d2), d2) : __fsub_rn(a2, 0.5f);
      double hubv = (double)h0 + (double)h1 + (double)h2v;
      double csv = 0.0;
      if (m > 0.f) {
        float ps = __fadd_rn(__fadd_rn(__fmul_rn(px,px), __fmul_rn(py,py)), __fmul_rn(pz,pz));
        float pn = (ps > 0.f) ? sqrtf(ps) : 0.f;
        float dotp = __fadd_rn(__fadd_rn(__fmul_rn(px,tox), __fmul_rn(py,toy)),
                               __fmul_rn(pz,toz));
        float den = fmaxf(__fmul_rn(pn, m), 1e-4f);
        csv = (double)__fdiv_rn(dotp, den);
      }
      if (boundary) {
        dfr = true;
        dhub = hubv; dcs = csv;
        if (cb == binA) atomicAdd(&h[(bits >> 10) & 0x7FF], 1);
        if (cb == binB) atomicAdd(&h2[(bits >> 10) & 0x7FF], 1);
      } else {
        c1 = 1;
        hub = hubv;
        if (m > 0.f) { cmd = 1; cs = csv; }
      }
    }
  }
  {
    unsigned long long mb = __ballot(dfr);
    int mcp = __popcll(mb);
    int bs = 0;
    if (lane == 0 && mcp > 0) bs = atomicAdd(uCnt, mcp);
    bs = __shfl(bs, 0, 64);
    if (dfr) {
      int pos = bs + __popcll(mb & ((1ULL << lane) - 1ULL));
      dBits[pos] = bits;
      dHC[pos] = make_double2(dhub, dcs);
    }
  }
  __syncthreads();
  for (int t = tid; t < HB; t += 256) {
    int a = h[t];
    if (a != 0) atomicAdd(&gh2A[t], a);
    int b = h2[t];
    if (b != 0) atomicAdd(&gh2B[t], b);
  }

  shH[tid] = hub; shC[tid] = cs; shN[tid] = c1; shM[tid] = cmd;
  __syncthreads();
  for (int off = 128; off > 0; off >>= 1) {
    if (tid < off) {
      shH[tid] += shH[tid+off];
      shC[tid] += shC[tid+off];
      shN[tid] += shN[tid+off];
      shM[tid] += shM[tid+off];
    }
    __syncthreads();
  }
  if (tid == 0) {
    atomicAdd(&sc->hub, shH[0]);
    atomicAdd(&sc->cosSum, shC[0]);
    atomicAdd(&sc->n1, shN[0]);
    atomicAdd(&sc->nmd, shM[0]);
    __threadfence();
    int d = atomicAdd(&sc->done2, 1);
    sLast = (d == nblocks - 1) ? 1 : 0;
  }
  __syncthreads();
  if (!sLast) return;
  __threadfence();   // acquire: all blocks' defer/gh2 writes + partial sums

  int U = atomicAdd(uCnt, 0);

  // ---- step 3: mid-level scan directly from global gh2A/gh2B ----
  {
    int a8[8], sA = 0;
    #pragma unroll
    for (int k = 0; k < 8; ++k) { a8[k] = gh2A[base8 + k]; sA += a8[k]; }
    int inclA = block_scan256(sA, ws);
    int accA = inclA - sA;
    #pragma unroll
    for (int k = 0; k < 8; ++k) {
      if (rA >= accA && rA < accA + a8[k]) { s_misc[4] = base8 + k; s_misc[5] = rA - accA; }
      accA += a8[k];
    }
    int b8[8], sB = 0;
    #pragma unroll
    for (int k = 0; k < 8; ++k) { b8[k] = gh2B[base8 + k]; sB += b8[k]; }
    int inclB = block_scan256(sB, ws);
    int accB = inclB - sB;
    #pragma unroll
    for (int k = 0; k < 8; ++k) {
      if (rB >= accB && rB < accB + b8[k]) { s_misc[6] = base8 + k; s_misc[7] = rB - accB; }
      accB += b8[k];
    }
  }
  __syncthreads();
  int subA = s_misc[4], subRA = s_misc[5], subB = s_misc[6], subRB = s_misc[7];

  // ---- step 4: low-level hist, ONE uint4-batched pass over dBits ----
  for (int t = tid; t < 1024; t += 256) { h[t] = 0; h2[t] = 0; }
  __syncthreads();
  {
    const uint4* b4 = (const uint4*)dBits;
    int nv = U >> 2;
    for (int v = tid; v < nv; v += 256) {
      uint4 u = b4[v];
      unsigned bb[4] = { u.x, u.y, u.z, u.w };
      #pragma unroll
      for (int k = 0; k < 4; ++k) {
        unsigned b0 = bb[k];
        int cb = (int)(b0 >> 21);
        if (cb == binA && (int)((b0 >> 10) & 0x7FF) == subA) atomicAdd(&h[b0 & 0x3FF], 1);
        if (cb == binB && (int)((b0 >> 10) & 0x7FF) == subB) atomicAdd(&h2[b0 & 0x3FF], 1);
      }
    }
    for (int t = (nv << 2) + tid; t < U; t += 256) {
      unsigned b0 = dBits[t];
      int cb = (int)(b0 >> 21);
      if (cb == binA && (int)((b0 >> 10) & 0x7FF) == subA) atomicAdd(&h[b0 & 0x3FF], 1);
      if (cb == binB && (int)((b0 >> 10) & 0x7FF) == subB) atomicAdd(&h2[b0 & 0x3FF], 1);
    }
  }
  __syncthreads();
  {
    int base4 = tid * 4;
    int la[4], sA = 0;
    #pragma unroll
    for (int k = 0; k < 4; ++k) { la[k] = h[base4 + k]; sA += la[k]; }
    int inclA = block_scan256(sA, ws);
    int accA = inclA - sA;
    #pragma unroll
    for (int k = 0; k < 4; ++k) {
      if (subRA >= accA && subRA < accA + la[k]) s_misc[0] = base4 + k;
      accA += la[k];
    }
    int lb4[4], sB = 0;
    #pragma unroll
    for (int k = 0; k < 4; ++k) { lb4[k] = h2[base4 + k]; sB += lb4[k]; }
    int inclB = block_scan256(sB, ws);
    int accB = inclB - sB;
    #pragma unroll
    for (int k = 0; k < 4; ++k) {
      if (subRB >= accB && subRB < accB + lb4[k]) s_misc[1] = base4 + k;
      accB += lb4[k];
    }
  }
  __syncthreads();
  if (tid == 0) {
    unsigned va = ((unsigned)binA << 21) | ((unsigned)subA << 10) | (unsigned)s_misc[0];
    unsigned vb = ((unsigned)binB << 21) | ((unsigned)subB << 10) | (unsigned)s_misc[1];
    double a = (double)__uint_as_float(va);
    double b = (double)__uint_as_float(vb);
    double th = (tfrac >= 0.5) ? (b - (b - a) * (1.0 - tfrac)) : (a + (b - a) * tfrac);
    sc->thresh = (float)th;
    sTh = (float)th;
  }
  __syncthreads();
  float th = sTh;

  // ---- step 5: deferred loss, contiguous stream over (dBits, dHC) ----
  double hub2 = 0.0, cs2 = 0.0;
  int c12 = 0, cmd2 = 0;
  for (int t = tid; t < U; t += 256) {
    unsigned v = dBits[t];
    float m = __uint_as_float(v);
    double2 hc = dHC[t];
    if (m <= th) {
      c12 += 1;
      hub2 += hc.x;
      if (m > 0.f) { cmd2 += 1; cs2 += hc.y; }
    }
  }
  shH[tid] = hub2; shC[tid] = cs2; shN[tid] = c12; shM[tid] = cmd2;
  __syncthreads();
  for (int off = 128; off > 0; off >>= 1) {
    if (tid < off) {
      shH[tid] += shH[tid+off];
      shC[tid] += shC[tid+off];
      shN[tid] += shN[tid+off];
      shM[tid] += shM[tid+off];
    }
    __syncthreads();
  }
  if (tid == 0) {
    double th_hub = atomicAdd(&sc->hub, 0.0) + shH[0];
    double th_cos = atomicAdd(&sc->cosSum, 0.0) + shC[0];
    int n1 = atomicAdd(&sc->n1, 0) + shN[0];
    int nmd = atomicAdd(&sc->nmd, 0) + shM[0];
    double l1 = (n1 > 0) ? th_hub / fmax((double)n1 * 3.0, 1.0) : 0.0;
    double ld = (nmd > 0) ? (1.0 - th_cos / fmax((double)nmd, 1.0)) : 0.0;
    out[0] = (float)l1;
    out[1] = (float)ld;
  }
}

extern "C" void kernel_launch(void* const* d_in, const int* in_sizes, int n_in,
                              void* d_out, int out_size, void* d_ws, size_t ws_size,
                              hipStream_t stream) {
  const float* pred  = (const float*)d_in[0];
  const float* grid  = (const float*)d_in[1];
  const int*   label = (const int*)d_in[2];
  const int*   batch = (const int*)d_in[3];
  int n = in_sizes[2];
  int mstride = n / 4;

  char* p = (char*)d_ws;
  auto take = [&](size_t bytes) -> char* {
    char* r = p;
    p += (bytes + 255) & ~(size_t)255;
    return r;
  };
  // ---- early-zero region (hipMemsetAsync): touched by k_scatter's atomics ----
  char* zbase1 = p;
  unsigned long long* vA = (unsigned long long*)take((size_t)SLOTS*8);
  unsigned long long* vB = (unsigned long long*)take((size_t)SLOTS*8);
  int*    lmask    = (int*)   take((size_t)SLOTS*4);
  int*    blCnt    = (int*)   take(16*4);
  float*  blSum    = (float*) take(48*4);
  size_t zbytes1 = (size_t)(p - zbase1);
  // ---- late-zero region (zeroed inside k_scatter; consumers run later) ----
  char* zbase2 = p;
  int*    codeCnt  = (int*)   take(NCODE*4);
  int*    missCnt  = (int*)   take(NCODE*4);
  int*    ghist    = (int*)   take((size_t)HB*4);
  int*    gh2A     = (int*)   take((size_t)HB*4);
  int*    gh2B     = (int*)   take((size_t)HB*4);
  int*    uCnt     = (int*)   take(4);
  Scalars* sc      = (Scalars*)take(sizeof(Scalars));
  size_t zbytes2 = (size_t)(p - zbase2);
  // ---- uninitialized buffers ----
  float4* pC       = (float4*)take((size_t)NCODE*CSTRIDE*16);
  float*  tgt      = (float*) take((size_t)n*3*4);
  float*  mag      = (float*) take((size_t)n*4);
  int*    missPart = (int*)   take((size_t)NCODE*mstride*4);
  unsigned* dBits  = (unsigned*)take((size_t)n*4);
  double2*  dHC    = (double2*) take((size_t)n*16);

  int nb = (n + 255) / 256;
  int grid2 = nb > ((SLOTS + 255) / 256) ? nb : ((SLOTS + 255) / 256);
  int spb = (SLOTS + grid2 - 1) / grid2;   // <= 256 by construction
  int nfb = NCODE * BPC;
  int nzi = (int)(zbytes2 / 4);

  double vi = 0.99 * (double)(n - 1);
  int r0 = (int)vi;
  int r1 = r0 + 1; if (r1 > n - 1) r1 = n - 1;
  double tfrac = vi - (double)r0;

  hipMemsetAsync(zbase1, 0, zbytes1, stream);
  k_scatter<<<nb, 256, 0, stream>>>(grid, label, batch, vA, vB, lmask,
                                    blCnt, blSum, (int*)zbase2, nzi, n);
  k_targets_prep<<<grid2, 256, 0, stream>>>(grid, label, batch, vA, vB, lmask,
                                            blCnt, blSum, pC, codeCnt,
                                            tgt, mag, ghist, missPart, missCnt,
                                            mstride, spb, n);
  k_fallback<<<nfb, 256, 0, stream>>>(grid, pC, vA, vB, codeCnt,
                                      missPart, missCnt, tgt, mag, ghist, mstride);
  k_loss_sel<<<nb, 256, 0, stream>>>(pred, grid, tgt, mag, ghist, gh2A, gh2B,
                                     dBits, dHC, uCnt, sc, (float*)d_out,
                                     n, nb, r0, r1, tfrac);
}